// Round 4
// baseline (31215.063 us; speedup 1.0000x reference)
//
#include <hip/hip_runtime.h>
#include <hip/hip_bf16.h>
#include <math.h>

// Problem constants
#define IMGS 3          // B*V
#define H0 256
#define W0 320
#define H1 128
#define W1 160
#define FHh 64
#define FWw 80
#define NPIX 5120       // FHh*FWw
#define ND 128
#define FC 32
#define NBLK 512        // persistent grid: 2 blocks/CU * 256 CUs (co-residency guaranteed)

// ---------------- helpers ----------------
__device__ inline float ldx(const float* p) { return *p; }
__device__ inline float ldx(const __hip_bfloat16* p) { return __bfloat162float(*p); }
__device__ inline void stx(float* p, float v) { *p = v; }
__device__ inline void stx(__hip_bfloat16* p, float v) { *p = __float2bfloat16(v); }

__device__ inline float sigm_(float x){ return 1.f/(1.f+__expf(-x)); }
__device__ inline float tanh_(float x){ return 1.f - 2.f/(__expf(2.f*x)+1.f); }

__device__ inline void inv3(const float* a, float* o) {
    float det = a[0]*(a[4]*a[8]-a[5]*a[7]) - a[1]*(a[3]*a[8]-a[5]*a[6]) + a[2]*(a[3]*a[7]-a[4]*a[6]);
    float id = 1.f/det;
    o[0]=(a[4]*a[8]-a[5]*a[7])*id; o[1]=(a[2]*a[7]-a[1]*a[8])*id; o[2]=(a[1]*a[5]-a[2]*a[4])*id;
    o[3]=(a[5]*a[6]-a[3]*a[8])*id; o[4]=(a[0]*a[8]-a[2]*a[6])*id; o[5]=(a[2]*a[3]-a[0]*a[5])*id;
    o[6]=(a[3]*a[7]-a[4]*a[6])*id; o[7]=(a[1]*a[6]-a[0]*a[7])*id; o[8]=(a[0]*a[4]-a[1]*a[3])*id;
}
__device__ inline void mm3(const float* A, const float* B, float* C) {
    for (int i=0;i<3;i++) for (int j=0;j<3;j++)
        C[i*3+j] = A[i*3+0]*B[0*3+j] + A[i*3+1]*B[1*3+j] + A[i*3+2]*B[2*3+j];
}
__device__ inline void mv3(const float* A, const float* x, float* y) {
    for (int i=0;i<3;i++) y[i] = A[i*3+0]*x[0]+A[i*3+1]*x[1]+A[i*3+2]*x[2];
}

// su layout (floats): [v*12+0..8]=M_v  [v*12+9..11]=b_v  [48..175]=depths  [176]=ds [177]=di
__global__ void k_setup(const float* __restrict__ cam, float* __restrict__ su) {
    if (threadIdx.x != 0 || blockIdx.x != 0) return;
    auto at = [&](int v,int e,int i,int j){ return cam[(v*2+e)*16 + i*4 + j]; };
    float R0[9], K0[9], t0[3], iR0[9], iK0[9];
    for (int i=0;i<3;i++){
        for (int j=0;j<3;j++){ R0[i*3+j]=at(0,0,i,j); K0[i*3+j]=at(0,1,i,j); }
        t0[i]=at(0,0,i,3);
    }
    inv3(R0,iR0); inv3(K0,iK0);
    float ds = at(0,1,3,0), di = at(0,1,3,1), de = at(0,1,3,3);
    for (int d=0; d<ND; d++) su[48+d] = ds + (de-ds)*(float)d/(float)(ND-1);
    su[176]=ds; su[177]=di;
    for (int v=0; v<3; v++){
        float Rv[9], Kv[9], tv[3];
        for (int i=0;i<3;i++){
            for (int j=0;j<3;j++){ Rv[i*3+j]=at(v,0,i,j); Kv[i*3+j]=at(v,1,i,j); }
            tv[i]=at(v,0,i,3);
        }
        float A[9], KA[9], M[9];
        mm3(Rv, iR0, A); mm3(Kv, A, KA); mm3(KA, iK0, M);
        float At0[3], tmp[3], bv[3];
        mv3(A, t0, At0);
        for (int i=0;i<3;i++) tmp[i]=tv[i]-At0[i];
        mv3(Kv, tmp, bv);
        for (int i=0;i<9;i++) su[v*12+i]=M[i];
        for (int i=0;i<3;i++) su[v*12+9+i]=bv[i];
    }
}

// ---------------- feature extractor ----------------
__global__ __launch_bounds__(256) void k_conv3x3(
    const float* __restrict__ in, const float* __restrict__ w, const float* __restrict__ bias,
    float* __restrict__ out, int Cin, int Hin, int Win, int Cout, int Hout, int Wout, int stride)
{
    int img = blockIdx.y / Cout, co = blockIdx.y % Cout;
    extern __shared__ float wsm[];
    for (int i = threadIdx.x; i < Cin*9; i += 256) wsm[i] = w[co*Cin*9 + i];
    __syncthreads();
    int p = blockIdx.x*256 + threadIdx.x;
    if (p >= Hout*Wout) return;
    int oy = p / Wout, ox = p - oy*Wout;
    const float* ib = in + (size_t)img*Cin*Hin*Win;
    float acc = bias ? bias[co] : 0.f;
    for (int ky=0; ky<3; ky++){
        int iy = oy*stride - 1 + ky;
        if ((unsigned)iy >= (unsigned)Hin) continue;
        for (int kx=0; kx<3; kx++){
            int ix = ox*stride - 1 + kx;
            if ((unsigned)ix >= (unsigned)Win) continue;
            const float* ip = ib + (size_t)iy*Win + ix;
            const float* wp = wsm + ky*3 + kx;
            for (int ci=0; ci<Cin; ci++)
                acc = fmaf(wp[ci*9], ip[(size_t)ci*Hin*Win], acc);
        }
    }
    out[((size_t)img*Cout + co)*Hout*Wout + p] = acc;
}

__global__ __launch_bounds__(256) void k_gnstats(
    const float* __restrict__ x, float* __restrict__ stats, int Cg, int HW)
{
    const float* p = x + (size_t)blockIdx.x * Cg * HW;
    int M = Cg*HW;
    float s1=0.f, s2=0.f;
    for (int i=threadIdx.x; i<M; i+=256){ float v=p[i]; s1+=v; s2=fmaf(v,v,s2); }
    __shared__ float a1[256], a2[256];
    a1[threadIdx.x]=s1; a2[threadIdx.x]=s2; __syncthreads();
    for (int s=128; s>0; s>>=1){
        if (threadIdx.x < s){ a1[threadIdx.x]+=a1[threadIdx.x+s]; a2[threadIdx.x]+=a2[threadIdx.x+s]; }
        __syncthreads();
    }
    if (threadIdx.x==0){
        float mean = a1[0]/(float)M;
        float var  = a2[0]/(float)M - mean*mean;
        stats[blockIdx.x*2]   = mean;
        stats[blockIdx.x*2+1] = rsqrtf(var + 1e-5f);
    }
}

__global__ __launch_bounds__(256) void k_gnapply(
    float* __restrict__ x, const float* __restrict__ stats,
    const float* __restrict__ gamma, const float* __restrict__ beta,
    int C, int HW, int CgHW, int total)
{
    int i = blockIdx.x*256 + threadIdx.x;
    if (i >= total) return;
    int ch  = (i / HW) % C;
    int grp = i / CgHW;
    float mean = stats[grp*2], rstd = stats[grp*2+1];
    float v = (x[i]-mean)*rstd*gamma[ch] + beta[ch];
    x[i] = fmaxf(v, 0.f);
}

// feats (img,c,n) -> (img,n,c)
__global__ __launch_bounds__(256) void k_transpose(
    const float* __restrict__ f, float* __restrict__ ft)
{
    int i = blockIdx.x*256 + threadIdx.x;
    if (i >= IMGS*FC*NPIX) return;
    int n = i % NPIX;
    int c = (i / NPIX) % FC;
    int im = i / (FC*NPIX);
    ft[((size_t)im*NPIX + n)*FC + c] = f[i];
}

// ---------------- warp + cost volume (channel-last out: [d][n][FC]) ----------------
template<typename TO>
__global__ __launch_bounds__(256) void k_warpcost(
    const float* __restrict__ ft, const float* __restrict__ su, TO* __restrict__ xb)
{
    int t = blockIdx.x*256 + threadIdx.x;
    int d = t / NPIX, n = t - d*NPIX;
    int py = n / FWw, px = n - py*FWw;
    float u = px + 0.5f, v = py + 0.5f;
    float depth = su[48 + d];
    float s1[FC], s2[FC], samp[FC];
    const float* f0 = ft + (size_t)n*FC;
#pragma unroll
    for (int c=0;c<FC;c++){ float f = f0[c]; s1[c] = f; s2[c] = f*f; }
    for (int vv=1; vv<3; vv++){
        const float* m = su + vv*12;
        float wx = fmaf(fmaf(m[0],u,fmaf(m[1],v,m[2])), depth, m[9]);
        float wy = fmaf(fmaf(m[3],u,fmaf(m[4],v,m[5])), depth, m[10]);
        float wz = fmaf(fmaf(m[6],u,fmaf(m[7],v,m[8])), depth, m[11]);
        float iz = 1.f/(wz + 1e-9f);
        float ix = wx*iz - 0.5f, iy = wy*iz - 0.5f;
        float x0 = floorf(ix), y0 = floorf(iy);
#pragma unroll
        for (int c=0;c<FC;c++) samp[c] = 0.f;
        const float* fv = ft + (size_t)vv*NPIX*FC;
        for (int dy=0; dy<2; dy++){
            for (int dx=0; dx<2; dx++){
                float xc = x0+(float)dx, yc = y0+(float)dy;
                if (xc < 0.f || xc > (float)(FWw-1) || yc < 0.f || yc > (float)(FHh-1)) continue;
                float wgt = (1.f - fabsf(ix-xc))*(1.f - fabsf(iy-yc));
                const float* fp = fv + ((size_t)((int)yc)*FWw + (int)xc)*FC;
#pragma unroll
                for (int c=0;c<FC;c++) samp[c] = fmaf(fp[c], wgt, samp[c]);
            }
        }
#pragma unroll
        for (int c=0;c<FC;c++){ s1[c] += samp[c]; s2[c] = fmaf(samp[c], samp[c], s2[c]); }
    }
    TO* ob = xb + ((size_t)d*NPIX + n)*FC;
#pragma unroll
    for (int c=0;c<FC;c++){
        float m1 = s1[c]*(1.f/3.f);
        float cost = s2[c]*(1.f/3.f) - m1*m1;
        stx(ob + c, -cost);   // GRU input is -cost
    }
}

// ---------------- persistent pipelined GRU scan ----------------
// All h/zg/rh buffers are channel-last: h1 [n][16], h2 [n][4], h3 [n][2].
// Pipeline (2 grid barriers per k):
//   phase A(k): zr1(d=k), zr2(d=k-1), zr3(d=k-2)
//   phase B(k): c1(k), c2(k-1), c3(k-2), prob(k-2) [prob recomputes h3new at its 9 taps]
// h buffers parity-double-buffered by depth index; writes/reads always opposite parity.
struct ScanArgs {
    const void* xv;                    // cost volume [d][n][32] (float or bf16)
    const float *wz1,*bz1,*wr1,*br1,*wc1,*bc1;
    const float *wz2,*bz2,*wr2,*br2,*wc2,*bc2;
    const float *wz3,*bz3,*wr3,*br3,*wc3,*bc3;
    const float *wp,*bp;
    float *h1a,*h1b,*h2a,*h2b,*h3a,*h3b;   // parity 0 / parity 1
    float *zg0,*rh0,*zg1,*rh1,*zg2,*rh2;
    float *reg;
    unsigned *bar;                     // [0]=cnt [1]=gen  (memset to 0 before launch)
};

__device__ inline void gsync(unsigned* bar)
{
    __syncthreads();
    if (threadIdx.x == 0) {
        __threadfence();               // release: make this block's writes visible
        unsigned* cnt = bar;
        unsigned* gen = bar + 1;
        unsigned g = __hip_atomic_load(gen, __ATOMIC_RELAXED, __HIP_MEMORY_SCOPE_AGENT);
        unsigned a = __hip_atomic_fetch_add(cnt, 1u, __ATOMIC_ACQ_REL, __HIP_MEMORY_SCOPE_AGENT);
        if (a == NBLK - 1u) {
            __hip_atomic_store(cnt, 0u, __ATOMIC_RELAXED, __HIP_MEMORY_SCOPE_AGENT);
            __hip_atomic_store(gen, g + 1u, __ATOMIC_RELEASE, __HIP_MEMORY_SCOPE_AGENT);
        } else {
            while (__hip_atomic_load(gen, __ATOMIC_RELAXED, __HIP_MEMORY_SCOPE_AGENT) == g)
                __builtin_amdgcn_s_sleep(2);
        }
        __threadfence();               // acquire: invalidate stale cached lines
    }
    __syncthreads();
}

template<typename TX>
__global__ __launch_bounds__(256, 2) void k_scan(ScanArgs S)
{
    const int bid = blockIdx.x, tid = threadIdx.x;
    // role decode: [0,320) gru1, [320,400) gru2, [400,440) gru3, [440,460) prob, rest idle
    int role, co = 0, n = 0;
    if      (bid < 320) { role = 0; co = bid/20;        n = (bid%20)*256 + tid; }
    else if (bid < 400) { role = 1; int i = bid - 320; co = i/20; n = (i%20)*256 + tid; }
    else if (bid < 440) { role = 2; int i = bid - 400; co = i/20; n = (i%20)*256 + tid; }
    else if (bid < 460) { role = 3; n = (bid-440)*256 + tid; }
    else role = 4;
    const int py = n / FWw, px = n - py*FWw;

    // block-uniform weight bases (scalar s_loads inside loops)
    const float *wzc=nullptr, *wrc=nullptr, *wcc=nullptr;
    float bzv=0.f, brv=0.f, bcv=0.f;
    if (role == 0){ wzc=S.wz1+co*432; wrc=S.wr1+co*432; wcc=S.wc1+co*432; bzv=S.bz1[co]; brv=S.br1[co]; bcv=S.bc1[co]; }
    if (role == 1){ wzc=S.wz2+co*180; wrc=S.wr2+co*180; wcc=S.wc2+co*180; bzv=S.bz2[co]; brv=S.br2[co]; bcv=S.bc2[co]; }
    if (role == 2){ wzc=S.wz3+co*54;  wrc=S.wr3+co*54;  wcc=S.wc3+co*54;  bzv=S.bz3[co]; brv=S.br3[co]; bcv=S.bc3[co]; }

    float zsave = 0.f;   // z gate carried A->B in registers

    for (int k = 0; k < ND + 2; ++k) {
        // ---------------- PHASE A ----------------
        if (role == 0 && k < ND) {
            const int d = k;
            const TX* xd = (const TX*)S.xv + (size_t)d*NPIX*FC;
            const float* h1o = ((d-1)&1) ? S.h1b : S.h1a;
            float az = bzv, ar = brv;
#pragma unroll 1
            for (int ky=0; ky<3; ky++){
                int qy = py + ky - 1; if ((unsigned)qy >= (unsigned)FHh) continue;
#pragma unroll 1
                for (int kx=0; kx<3; kx++){
                    int qx = px + kx - 1; if ((unsigned)qx >= (unsigned)FWw) continue;
                    int q = qy*FWw + qx, j = ky*3 + kx;
                    const TX* xp = xd + (size_t)q*FC;
#pragma unroll
                    for (int ci=0; ci<32; ci++){
                        float v = ldx(xp + ci);
                        az = fmaf(wzc[ci*9+j], v, az);
                        ar = fmaf(wrc[ci*9+j], v, ar);
                    }
                    const float* hp = h1o + q*16;
#pragma unroll
                    for (int ci=0; ci<16; ci++){
                        float v = hp[ci];
                        az = fmaf(wzc[(32+ci)*9+j], v, az);
                        ar = fmaf(wrc[(32+ci)*9+j], v, ar);
                    }
                }
            }
            float z = sigm_(az), r = sigm_(ar);
            zsave = z;
            S.zg0[n*16+co] = z;
            S.rh0[n*16+co] = r * h1o[n*16+co];
        } else if (role == 1 && k >= 1 && k <= ND) {
            const int d = k - 1;
            const float* x2  = (d&1) ? S.h1b : S.h1a;      // h1 new of step d
            const float* h2o = ((d-1)&1) ? S.h2b : S.h2a;
            float az = bzv, ar = brv;
#pragma unroll 1
            for (int ky=0; ky<3; ky++){
                int qy = py + ky - 1; if ((unsigned)qy >= (unsigned)FHh) continue;
#pragma unroll 1
                for (int kx=0; kx<3; kx++){
                    int qx = px + kx - 1; if ((unsigned)qx >= (unsigned)FWw) continue;
                    int q = qy*FWw + qx, j = ky*3 + kx;
                    const float* xp = x2 + q*16;
#pragma unroll
                    for (int ci=0; ci<16; ci++){
                        float v = xp[ci];
                        az = fmaf(wzc[ci*9+j], v, az);
                        ar = fmaf(wrc[ci*9+j], v, ar);
                    }
                    const float* hp = h2o + q*4;
#pragma unroll
                    for (int ci=0; ci<4; ci++){
                        float v = hp[ci];
                        az = fmaf(wzc[(16+ci)*9+j], v, az);
                        ar = fmaf(wrc[(16+ci)*9+j], v, ar);
                    }
                }
            }
            float z = sigm_(az), r = sigm_(ar);
            zsave = z;
            S.zg1[n*4+co] = z;
            S.rh1[n*4+co] = r * h2o[n*4+co];
        } else if (role == 2 && k >= 2) {
            const int d = k - 2;
            const float* x3  = (d&1) ? S.h2b : S.h2a;      // h2 new of step d
            const float* h3o = ((d-1)&1) ? S.h3b : S.h3a;
            float az = bzv, ar = brv;
#pragma unroll 1
            for (int ky=0; ky<3; ky++){
                int qy = py + ky - 1; if ((unsigned)qy >= (unsigned)FHh) continue;
#pragma unroll 1
                for (int kx=0; kx<3; kx++){
                    int qx = px + kx - 1; if ((unsigned)qx >= (unsigned)FWw) continue;
                    int q = qy*FWw + qx, j = ky*3 + kx;
                    const float* xp = x3 + q*4;
#pragma unroll
                    for (int ci=0; ci<4; ci++){
                        float v = xp[ci];
                        az = fmaf(wzc[ci*9+j], v, az);
                        ar = fmaf(wrc[ci*9+j], v, ar);
                    }
                    const float* hp = h3o + q*2;
#pragma unroll
                    for (int ci=0; ci<2; ci++){
                        float v = hp[ci];
                        az = fmaf(wzc[(4+ci)*9+j], v, az);
                        ar = fmaf(wrc[(4+ci)*9+j], v, ar);
                    }
                }
            }
            float z = sigm_(az), r = sigm_(ar);
            zsave = z;
            S.zg2[n*2+co] = z;
            S.rh2[n*2+co] = r * h3o[n*2+co];
        }
        gsync(S.bar);

        // ---------------- PHASE B ----------------
        if (role == 0 && k < ND) {
            const int d = k;
            const TX* xd = (const TX*)S.xv + (size_t)d*NPIX*FC;
            const float* h1o = ((d-1)&1) ? S.h1b : S.h1a;
            float*       h1n = (d&1)     ? S.h1b : S.h1a;
            float ac = bcv;
#pragma unroll 1
            for (int ky=0; ky<3; ky++){
                int qy = py + ky - 1; if ((unsigned)qy >= (unsigned)FHh) continue;
#pragma unroll 1
                for (int kx=0; kx<3; kx++){
                    int qx = px + kx - 1; if ((unsigned)qx >= (unsigned)FWw) continue;
                    int q = qy*FWw + qx, j = ky*3 + kx;
                    const TX* xp = xd + (size_t)q*FC;
#pragma unroll
                    for (int ci=0; ci<32; ci++)
                        ac = fmaf(wcc[ci*9+j], ldx(xp + ci), ac);
                    const float* rp = S.rh0 + q*16;
#pragma unroll
                    for (int ci=0; ci<16; ci++)
                        ac = fmaf(wcc[(32+ci)*9+j], rp[ci], ac);
                }
            }
            float cg = tanh_(ac);
            float z = zsave;
            h1n[n*16+co] = z*h1o[n*16+co] + (1.f - z)*cg;
        } else if (role == 1 && k >= 1 && k <= ND) {
            const int d = k - 1;
            const float* x2  = (d&1) ? S.h1b : S.h1a;
            const float* h2o = ((d-1)&1) ? S.h2b : S.h2a;
            float*       h2n = (d&1)     ? S.h2b : S.h2a;
            float ac = bcv;
#pragma unroll 1
            for (int ky=0; ky<3; ky++){
                int qy = py + ky - 1; if ((unsigned)qy >= (unsigned)FHh) continue;
#pragma unroll 1
                for (int kx=0; kx<3; kx++){
                    int qx = px + kx - 1; if ((unsigned)qx >= (unsigned)FWw) continue;
                    int q = qy*FWw + qx, j = ky*3 + kx;
                    const float* xp = x2 + q*16;
#pragma unroll
                    for (int ci=0; ci<16; ci++)
                        ac = fmaf(wcc[ci*9+j], xp[ci], ac);
                    const float* rp = S.rh1 + q*4;
#pragma unroll
                    for (int ci=0; ci<4; ci++)
                        ac = fmaf(wcc[(16+ci)*9+j], rp[ci], ac);
                }
            }
            float cg = tanh_(ac);
            float z = zsave;
            h2n[n*4+co] = z*h2o[n*4+co] + (1.f - z)*cg;
        } else if (role == 2 && k >= 2) {
            const int d = k - 2;
            const float* x3  = (d&1) ? S.h2b : S.h2a;
            const float* h3o = ((d-1)&1) ? S.h3b : S.h3a;
            float*       h3n = (d&1)     ? S.h3b : S.h3a;
            float ac = bcv;
#pragma unroll 1
            for (int ky=0; ky<3; ky++){
                int qy = py + ky - 1; if ((unsigned)qy >= (unsigned)FHh) continue;
#pragma unroll 1
                for (int kx=0; kx<3; kx++){
                    int qx = px + kx - 1; if ((unsigned)qx >= (unsigned)FWw) continue;
                    int q = qy*FWw + qx, j = ky*3 + kx;
                    const float* xp = x3 + q*4;
#pragma unroll
                    for (int ci=0; ci<4; ci++)
                        ac = fmaf(wcc[ci*9+j], xp[ci], ac);
                    const float* rp = S.rh2 + q*2;
                    ac = fmaf(wcc[4*9+j], rp[0], ac);
                    ac = fmaf(wcc[5*9+j], rp[1], ac);
                }
            }
            float cg = tanh_(ac);
            float z = zsave;
            h3n[n*2+co] = z*h3o[n*2+co] + (1.f - z)*cg;
        } else if (role == 3 && k >= 2) {
            // prob(d): recompute h3new at the 9 taps from zg2/rh2/h2new/h3old (no extra barrier)
            const int d = k - 2;
            const float* x3  = (d&1) ? S.h2b : S.h2a;
            const float* h3o = ((d-1)&1) ? S.h3b : S.h3a;
            float a = S.bp[0];
#pragma unroll 1
            for (int ky=0; ky<3; ky++){
                int qy = py + ky - 1; if ((unsigned)qy >= (unsigned)FHh) continue;
#pragma unroll 1
                for (int kx=0; kx<3; kx++){
                    int qx = px + kx - 1; if ((unsigned)qx >= (unsigned)FWw) continue;
                    int q = qy*FWw + qx;
#pragma unroll 1
                    for (int c2=0; c2<2; c2++){
                        const float* wc3c = S.wc3 + c2*54;
                        float ac = S.bc3[c2];
#pragma unroll 1
                        for (int jy=0; jy<3; jy++){
                            int ry = qy + jy - 1; if ((unsigned)ry >= (unsigned)FHh) continue;
#pragma unroll 1
                            for (int jx=0; jx<3; jx++){
                                int rx = qx + jx - 1; if ((unsigned)rx >= (unsigned)FWw) continue;
                                int rq = ry*FWw + rx, jj = jy*3 + jx;
                                const float* xp = x3 + rq*4;
#pragma unroll
                                for (int ci=0; ci<4; ci++)
                                    ac = fmaf(wc3c[ci*9+jj], xp[ci], ac);
                                const float* rp = S.rh2 + rq*2;
                                ac = fmaf(wc3c[4*9+jj], rp[0], ac);
                                ac = fmaf(wc3c[5*9+jj], rp[1], ac);
                            }
                        }
                        float cg = tanh_(ac);
                        float z = S.zg2[q*2+c2];
                        float h3n = z*h3o[q*2+c2] + (1.f - z)*cg;
                        a = fmaf(S.wp[c2*9 + ky*3 + kx], h3n, a);
                    }
                }
            }
            S.reg[(size_t)d*NPIX + n] = a;
        }
        gsync(S.bar);
    }
}

// ---------------- softmax / depth regression (f32 out) ----------------
__global__ __launch_bounds__(256) void k_final(
    const float* __restrict__ reg, const float* __restrict__ su, float* __restrict__ out)
{
    int n = blockIdx.x*256 + threadIdx.x;
    if (n >= NPIX) return;
    float m = -1e30f;
    for (int d=0; d<ND; d++) m = fmaxf(m, reg[(size_t)d*NPIX + n]);
    float s = 0.f, acc = 0.f;
    for (int d=0; d<ND; d++){
        float e = expf(reg[(size_t)d*NPIX + n] - m);
        s += e;
        acc = fmaf(e, su[48+d], acc);
    }
    float inv_s = 1.f/s;
    float pred = acc * inv_s;
    float ds = su[176], di = su[177];
    int i0 = (int)floorf((pred - ds)/di);
    float pm = 0.f;
    for (int k=0; k<4; k++){
        int g = min(max(i0 - 1 + k, 0), ND-1);
        pm += expf(reg[(size_t)g*NPIX + n] - m);
    }
    pm *= inv_s;
    out[n]        = pred;
    out[NPIX + n] = pm;
}

// ---------------- host orchestration ----------------
extern "C" void kernel_launch(void* const* d_in, const int* in_sizes, int n_in,
                              void* d_out, int out_size, void* d_ws, size_t ws_size,
                              hipStream_t stream)
{
    (void)in_sizes; (void)n_in; (void)out_size;
    const float* img   = (const float*)d_in[0];
    const float* cam   = (const float*)d_in[1];
    const float* fe_w0 = (const float*)d_in[2];
    const float* fe_g0 = (const float*)d_in[3];
    const float* fe_b0 = (const float*)d_in[4];
    const float* fe_w1 = (const float*)d_in[5];
    const float* fe_g1 = (const float*)d_in[6];
    const float* fe_b1 = (const float*)d_in[7];
    const float* fe_w2 = (const float*)d_in[8];
    const float* fe_g2 = (const float*)d_in[9];
    const float* fe_b2 = (const float*)d_in[10];
    const float* fe_w3 = (const float*)d_in[11];
    const float* fe_b3 = (const float*)d_in[12];
    const float* gw[3][3]; const float* gb[3][3];
    for (int i=0;i<3;i++) for (int g=0; g<3; g++){
        gw[i][g] = (const float*)d_in[13 + i*6 + g*2];
        gb[i][g] = (const float*)d_in[13 + i*6 + g*2 + 1];
    }
    const float* prob_w = (const float*)d_in[31];
    const float* prob_b = (const float*)d_in[32];
    float* out = (float*)d_out;

    // workspace layout
    char* base = (char*)d_ws;
    size_t off = 0;
    auto alloc = [&](size_t bytes)->char*{
        char* p = base + off; off += (bytes + 255) & ~(size_t)255; return p;
    };
    float* su     = (float*)alloc(256*4);
    float* stats  = (float*)alloc(64*4);
    unsigned* bar = (unsigned*)alloc(2*4);
    float* buf0   = (float*)alloc((size_t)IMGS*8*H0*W0*4);
    float* buf1   = (float*)alloc((size_t)IMGS*16*H1*W1*4);
    float* buf2   = (float*)alloc((size_t)IMGS*32*NPIX*4);
    float* feats  = (float*)alloc((size_t)IMGS*32*NPIX*4);
    float* featst = (float*)alloc((size_t)IMGS*NPIX*FC*4);
    float* reg    = (float*)alloc((size_t)ND*NPIX*4);
    float* h1a = (float*)alloc(16*NPIX*4); float* h1b = (float*)alloc(16*NPIX*4);
    float* h2a = (float*)alloc(4*NPIX*4);  float* h2b = (float*)alloc(4*NPIX*4);
    float* h3a = (float*)alloc(2*NPIX*4);  float* h3b = (float*)alloc(2*NPIX*4);
    float* zg0 = (float*)alloc(16*NPIX*4);
    float* rh0 = (float*)alloc(16*NPIX*4);
    float* zg1 = (float*)alloc(4*NPIX*4);
    float* rh1 = (float*)alloc(4*NPIX*4);
    float* zg2 = (float*)alloc(2*NPIX*4);
    float* rh2 = (float*)alloc(2*NPIX*4);
    size_t off_common = off;
    // cost volume: f32 if workspace allows, else bf16
    bool xf32 = (ws_size >= off_common + (size_t)ND*FC*NPIX*4);
    void* xbuf = (void*)(base + off_common);

    // zero odd-parity h buffers (read at d=0 as h(-1)) and barrier state
    (void)hipMemsetAsync(h1b, 0, 16*NPIX*4, stream);
    (void)hipMemsetAsync(h2b, 0, 4*NPIX*4, stream);
    (void)hipMemsetAsync(h3b, 0, 2*NPIX*4, stream);
    (void)hipMemsetAsync(bar, 0, 2*4, stream);

    k_setup<<<1, 64, 0, stream>>>(cam, su);

    // ---- feature extraction ----
    k_conv3x3<<<dim3((H0*W0+255)/256, IMGS*8), 256, 3*9*4, stream>>>(
        img, fe_w0, nullptr, buf0, 3, H0, W0, 8, H0, W0, 1);
    k_gnstats<<<IMGS*1, 256, 0, stream>>>(buf0, stats, 8, H0*W0);
    k_gnapply<<<(IMGS*8*H0*W0+255)/256, 256, 0, stream>>>(
        buf0, stats, fe_g0, fe_b0, 8, H0*W0, 8*H0*W0, IMGS*8*H0*W0);
    k_conv3x3<<<dim3((H1*W1+255)/256, IMGS*16), 256, 8*9*4, stream>>>(
        buf0, fe_w1, nullptr, buf1, 8, H0, W0, 16, H1, W1, 2);
    k_gnstats<<<IMGS*2, 256, 0, stream>>>(buf1, stats, 8, H1*W1);
    k_gnapply<<<(IMGS*16*H1*W1+255)/256, 256, 0, stream>>>(
        buf1, stats, fe_g1, fe_b1, 16, H1*W1, 8*H1*W1, IMGS*16*H1*W1);
    k_conv3x3<<<dim3((NPIX+255)/256, IMGS*32), 256, 16*9*4, stream>>>(
        buf1, fe_w2, nullptr, buf2, 16, H1, W1, 32, FHh, FWw, 2);
    k_gnstats<<<IMGS*4, 256, 0, stream>>>(buf2, stats, 8, NPIX);
    k_gnapply<<<(IMGS*32*NPIX+255)/256, 256, 0, stream>>>(
        buf2, stats, fe_g2, fe_b2, 32, NPIX, 8*NPIX, IMGS*32*NPIX);
    k_conv3x3<<<dim3((NPIX+255)/256, IMGS*32), 256, 32*9*4, stream>>>(
        buf2, fe_w3, fe_b3, feats, 32, FHh, FWw, 32, FHh, FWw, 1);
    k_transpose<<<(IMGS*FC*NPIX+255)/256, 256, 0, stream>>>(feats, featst);

    // ---- warp + cost volume ----
    if (xf32) k_warpcost<float><<<ND*NPIX/256, 256, 0, stream>>>(featst, su, (float*)xbuf);
    else      k_warpcost<__hip_bfloat16><<<ND*NPIX/256, 256, 0, stream>>>(featst, su, (__hip_bfloat16*)xbuf);

    // ---- persistent pipelined GRU scan (1 kernel, 2 barriers/step) ----
    ScanArgs S;
    S.xv = xbuf;
    S.wz1=gw[0][0]; S.bz1=gb[0][0]; S.wr1=gw[0][1]; S.br1=gb[0][1]; S.wc1=gw[0][2]; S.bc1=gb[0][2];
    S.wz2=gw[1][0]; S.bz2=gb[1][0]; S.wr2=gw[1][1]; S.br2=gb[1][1]; S.wc2=gw[1][2]; S.bc2=gb[1][2];
    S.wz3=gw[2][0]; S.bz3=gb[2][0]; S.wr3=gw[2][1]; S.br3=gb[2][1]; S.wc3=gw[2][2]; S.bc3=gb[2][2];
    S.wp=prob_w; S.bp=prob_b;
    S.h1a=h1a; S.h1b=h1b; S.h2a=h2a; S.h2b=h2b; S.h3a=h3a; S.h3b=h3b;
    S.zg0=zg0; S.rh0=rh0; S.zg1=zg1; S.rh1=rh1; S.zg2=zg2; S.rh2=rh2;
    S.reg=reg; S.bar=bar;
    if (xf32) k_scan<float><<<NBLK, 256, 0, stream>>>(S);
    else      k_scan<__hip_bfloat16><<<NBLK, 256, 0, stream>>>(S);

    // ---- softmax + depth regression + prob map ----
    k_final<<<NPIX/256, 256, 0, stream>>>(reg, su, out);
}

// Round 5
// 16556.665 us; speedup vs baseline: 1.8853x; 1.8853x over previous
//
#include <hip/hip_runtime.h>
#include <hip/hip_bf16.h>
#include <math.h>

// Problem constants
#define IMGS 3          // B*V
#define H0 256
#define W0 320
#define H1 128
#define W1 160
#define FHh 64
#define FWw 80
#define NPIX 5120       // FHh*FWw
#define ND 128
#define FC 32
#define NBLK 460        // persistent grid; launch_bounds(256,2) -> 512-block capacity >= 460

// ---------------- helpers ----------------
__device__ inline float ldx(const float* p) { return *p; }
__device__ inline float ldx(const __hip_bfloat16* p) { return __bfloat162float(*p); }
__device__ inline void stx(float* p, float v) { *p = v; }
__device__ inline void stx(__hip_bfloat16* p, float v) { *p = __float2bfloat16(v); }

__device__ inline float sigm_(float x){ return 1.f/(1.f+__expf(-x)); }
__device__ inline float tanh_(float x){ return 1.f - 2.f/(__expf(2.f*x)+1.f); }

__device__ inline void inv3(const float* a, float* o) {
    float det = a[0]*(a[4]*a[8]-a[5]*a[7]) - a[1]*(a[3]*a[8]-a[5]*a[6]) + a[2]*(a[3]*a[7]-a[4]*a[6]);
    float id = 1.f/det;
    o[0]=(a[4]*a[8]-a[5]*a[7])*id; o[1]=(a[2]*a[7]-a[1]*a[8])*id; o[2]=(a[1]*a[5]-a[2]*a[4])*id;
    o[3]=(a[5]*a[6]-a[3]*a[8])*id; o[4]=(a[0]*a[8]-a[2]*a[6])*id; o[5]=(a[2]*a[3]-a[0]*a[5])*id;
    o[6]=(a[3]*a[7]-a[4]*a[6])*id; o[7]=(a[1]*a[6]-a[0]*a[7])*id; o[8]=(a[0]*a[4]-a[1]*a[3])*id;
}
__device__ inline void mm3(const float* A, const float* B, float* C) {
    for (int i=0;i<3;i++) for (int j=0;j<3;j++)
        C[i*3+j] = A[i*3+0]*B[0*3+j] + A[i*3+1]*B[1*3+j] + A[i*3+2]*B[2*3+j];
}
__device__ inline void mv3(const float* A, const float* x, float* y) {
    for (int i=0;i<3;i++) y[i] = A[i*3+0]*x[0]+A[i*3+1]*x[1]+A[i*3+2]*x[2];
}

// su layout (floats): [v*12+0..8]=M_v  [v*12+9..11]=b_v  [48..175]=depths  [176]=ds [177]=di
__global__ void k_setup(const float* __restrict__ cam, float* __restrict__ su) {
    if (threadIdx.x != 0 || blockIdx.x != 0) return;
    auto at = [&](int v,int e,int i,int j){ return cam[(v*2+e)*16 + i*4 + j]; };
    float R0[9], K0[9], t0[3], iR0[9], iK0[9];
    for (int i=0;i<3;i++){
        for (int j=0;j<3;j++){ R0[i*3+j]=at(0,0,i,j); K0[i*3+j]=at(0,1,i,j); }
        t0[i]=at(0,0,i,3);
    }
    inv3(R0,iR0); inv3(K0,iK0);
    float ds = at(0,1,3,0), di = at(0,1,3,1), de = at(0,1,3,3);
    for (int d=0; d<ND; d++) su[48+d] = ds + (de-ds)*(float)d/(float)(ND-1);
    su[176]=ds; su[177]=di;
    for (int v=0; v<3; v++){
        float Rv[9], Kv[9], tv[3];
        for (int i=0;i<3;i++){
            for (int j=0;j<3;j++){ Rv[i*3+j]=at(v,0,i,j); Kv[i*3+j]=at(v,1,i,j); }
            tv[i]=at(v,0,i,3);
        }
        float A[9], KA[9], M[9];
        mm3(Rv, iR0, A); mm3(Kv, A, KA); mm3(KA, iK0, M);
        float At0[3], tmp[3], bv[3];
        mv3(A, t0, At0);
        for (int i=0;i<3;i++) tmp[i]=tv[i]-At0[i];
        mv3(Kv, tmp, bv);
        for (int i=0;i<9;i++) su[v*12+i]=M[i];
        for (int i=0;i<3;i++) su[v*12+9+i]=bv[i];
    }
}

// ---------------- feature extractor ----------------
__global__ __launch_bounds__(256) void k_conv3x3(
    const float* __restrict__ in, const float* __restrict__ w, const float* __restrict__ bias,
    float* __restrict__ out, int Cin, int Hin, int Win, int Cout, int Hout, int Wout, int stride)
{
    int img = blockIdx.y / Cout, co = blockIdx.y % Cout;
    extern __shared__ float wsm[];
    for (int i = threadIdx.x; i < Cin*9; i += 256) wsm[i] = w[co*Cin*9 + i];
    __syncthreads();
    int p = blockIdx.x*256 + threadIdx.x;
    if (p >= Hout*Wout) return;
    int oy = p / Wout, ox = p - oy*Wout;
    const float* ib = in + (size_t)img*Cin*Hin*Win;
    float acc = bias ? bias[co] : 0.f;
    for (int ky=0; ky<3; ky++){
        int iy = oy*stride - 1 + ky;
        if ((unsigned)iy >= (unsigned)Hin) continue;
        for (int kx=0; kx<3; kx++){
            int ix = ox*stride - 1 + kx;
            if ((unsigned)ix >= (unsigned)Win) continue;
            const float* ip = ib + (size_t)iy*Win + ix;
            const float* wp = wsm + ky*3 + kx;
            for (int ci=0; ci<Cin; ci++)
                acc = fmaf(wp[ci*9], ip[(size_t)ci*Hin*Win], acc);
        }
    }
    out[((size_t)img*Cout + co)*Hout*Wout + p] = acc;
}

__global__ __launch_bounds__(256) void k_gnstats(
    const float* __restrict__ x, float* __restrict__ stats, int Cg, int HW)
{
    const float* p = x + (size_t)blockIdx.x * Cg * HW;
    int M = Cg*HW;
    float s1=0.f, s2=0.f;
    for (int i=threadIdx.x; i<M; i+=256){ float v=p[i]; s1+=v; s2=fmaf(v,v,s2); }
    __shared__ float a1[256], a2[256];
    a1[threadIdx.x]=s1; a2[threadIdx.x]=s2; __syncthreads();
    for (int s=128; s>0; s>>=1){
        if (threadIdx.x < s){ a1[threadIdx.x]+=a1[threadIdx.x+s]; a2[threadIdx.x]+=a2[threadIdx.x+s]; }
        __syncthreads();
    }
    if (threadIdx.x==0){
        float mean = a1[0]/(float)M;
        float var  = a2[0]/(float)M - mean*mean;
        stats[blockIdx.x*2]   = mean;
        stats[blockIdx.x*2+1] = rsqrtf(var + 1e-5f);
    }
}

__global__ __launch_bounds__(256) void k_gnapply(
    float* __restrict__ x, const float* __restrict__ stats,
    const float* __restrict__ gamma, const float* __restrict__ beta,
    int C, int HW, int CgHW, int total)
{
    int i = blockIdx.x*256 + threadIdx.x;
    if (i >= total) return;
    int ch  = (i / HW) % C;
    int grp = i / CgHW;
    float mean = stats[grp*2], rstd = stats[grp*2+1];
    float v = (x[i]-mean)*rstd*gamma[ch] + beta[ch];
    x[i] = fmaxf(v, 0.f);
}

// feats (img,c,n) -> (img,n,c)
__global__ __launch_bounds__(256) void k_transpose(
    const float* __restrict__ f, float* __restrict__ ft)
{
    int i = blockIdx.x*256 + threadIdx.x;
    if (i >= IMGS*FC*NPIX) return;
    int n = i % NPIX;
    int c = (i / NPIX) % FC;
    int im = i / (FC*NPIX);
    ft[((size_t)im*NPIX + n)*FC + c] = f[i];
}

// ---------------- warp + cost volume (channel-last out: [d][n][FC]) ----------------
template<typename TO>
__global__ __launch_bounds__(256) void k_warpcost(
    const float* __restrict__ ft, const float* __restrict__ su, TO* __restrict__ xb)
{
    int t = blockIdx.x*256 + threadIdx.x;
    int d = t / NPIX, n = t - d*NPIX;
    int py = n / FWw, px = n - py*FWw;
    float u = px + 0.5f, v = py + 0.5f;
    float depth = su[48 + d];
    float s1[FC], s2[FC], samp[FC];
    const float* f0 = ft + (size_t)n*FC;
#pragma unroll
    for (int c=0;c<FC;c++){ float f = f0[c]; s1[c] = f; s2[c] = f*f; }
    for (int vv=1; vv<3; vv++){
        const float* m = su + vv*12;
        float wx = fmaf(fmaf(m[0],u,fmaf(m[1],v,m[2])), depth, m[9]);
        float wy = fmaf(fmaf(m[3],u,fmaf(m[4],v,m[5])), depth, m[10]);
        float wz = fmaf(fmaf(m[6],u,fmaf(m[7],v,m[8])), depth, m[11]);
        float iz = 1.f/(wz + 1e-9f);
        float ix = wx*iz - 0.5f, iy = wy*iz - 0.5f;
        float x0 = floorf(ix), y0 = floorf(iy);
#pragma unroll
        for (int c=0;c<FC;c++) samp[c] = 0.f;
        const float* fv = ft + (size_t)vv*NPIX*FC;
        for (int dy=0; dy<2; dy++){
            for (int dx=0; dx<2; dx++){
                float xc = x0+(float)dx, yc = y0+(float)dy;
                if (xc < 0.f || xc > (float)(FWw-1) || yc < 0.f || yc > (float)(FHh-1)) continue;
                float wgt = (1.f - fabsf(ix-xc))*(1.f - fabsf(iy-yc));
                const float* fp = fv + ((size_t)((int)yc)*FWw + (int)xc)*FC;
#pragma unroll
                for (int c=0;c<FC;c++) samp[c] = fmaf(fp[c], wgt, samp[c]);
            }
        }
#pragma unroll
        for (int c=0;c<FC;c++){ s1[c] += samp[c]; s2[c] = fmaf(samp[c], samp[c], s2[c]); }
    }
    TO* ob = xb + ((size_t)d*NPIX + n)*FC;
#pragma unroll
    for (int c=0;c<FC;c++){
        float m1 = s1[c]*(1.f/3.f);
        float cost = s2[c]*(1.f/3.f) - m1*m1;
        stx(ob + c, -cost);   // GRU input is -cost
    }
}

// ---------------- persistent pipelined GRU scan ----------------
// Pipeline (2 grid barriers per k):
//   phase A(k): zr1(d=k), zr2(d=k-1), zr3(d=k-2)
//   phase B(k): c1(k), c2(k-1), c3(k-2), prob(k-2) [prob recomputes h3new at its 9 taps]
// h buffers parity-double-buffered by depth index.
struct ScanArgs {
    const void* xv;                    // cost volume [d][n][32] (float or bf16)
    const float *wz1,*bz1,*wr1,*br1,*wc1,*bc1;
    const float *wz2,*bz2,*wr2,*br2,*wc2,*bc2;
    const float *wz3,*bz3,*wr3,*br3,*wc3,*bc3;
    const float *wp,*bp;
    float *h1a,*h1b,*h2a,*h2b,*h3a,*h3b;   // parity 0 / parity 1
    float *zg0,*rh0,*zg1,*rh1,*zg2,*rh2;
    float *reg;
    unsigned *gen;                     // 1 word (own cacheline)
    unsigned *arrive;                  // NBLK slots, stride 32 u32 (128B), memset 0
};

// Flag-array barrier: NO same-line atomic RMWs (round-4 lesson: 512 serialized
// fetch_adds on one line = ~115us/barrier). Arrival stores go to per-block
// cachelines (parallel); block 0 gathers with 256 threads in parallel; release
// via one broadcast word that everyone read-polls.
__device__ inline void gsync(const ScanArgs& S, unsigned tgt)
{
    __syncthreads();
    if (threadIdx.x == 0) {
        __threadfence();   // release: L2 writeback so peers (other XCDs) see our data
        __hip_atomic_store(&S.arrive[blockIdx.x * 32], tgt,
                           __ATOMIC_RELAXED, __HIP_MEMORY_SCOPE_AGENT);
    }
    if (blockIdx.x == 0) {
        for (int i = threadIdx.x; i < NBLK; i += 256) {
            while (__hip_atomic_load(&S.arrive[i * 32],
                                     __ATOMIC_RELAXED, __HIP_MEMORY_SCOPE_AGENT) < tgt)
                __builtin_amdgcn_s_sleep(1);
        }
        __syncthreads();
        if (threadIdx.x == 0)
            __hip_atomic_store(S.gen, tgt, __ATOMIC_RELEASE, __HIP_MEMORY_SCOPE_AGENT);
    }
    if (threadIdx.x == 0) {
        while (__hip_atomic_load(S.gen, __ATOMIC_RELAXED, __HIP_MEMORY_SCOPE_AGENT) < tgt)
            __builtin_amdgcn_s_sleep(1);
        __threadfence();   // acquire: invalidate stale L2/L1 lines
    }
    __syncthreads();
}

template<typename TX>
__global__ __launch_bounds__(256, 2) void k_scan(ScanArgs S)
{
    const int bid = blockIdx.x, tid = threadIdx.x;
    // role decode: [0,320) gru1, [320,400) gru2, [400,440) gru3, [440,460) prob
    int role, co = 0, n = 0;
    if      (bid < 320) { role = 0; co = bid/20;        n = (bid%20)*256 + tid; }
    else if (bid < 400) { role = 1; int i = bid - 320; co = i/20; n = (i%20)*256 + tid; }
    else if (bid < 440) { role = 2; int i = bid - 400; co = i/20; n = (i%20)*256 + tid; }
    else                { role = 3; n = (bid-440)*256 + tid; }
    const int py = n / FWw, px = n - py*FWw;

    // block-uniform weight bases (scalar s_loads inside loops)
    const float *wzc=nullptr, *wrc=nullptr, *wcc=nullptr;
    float bzv=0.f, brv=0.f, bcv=0.f;
    if (role == 0){ wzc=S.wz1+co*432; wrc=S.wr1+co*432; wcc=S.wc1+co*432; bzv=S.bz1[co]; brv=S.br1[co]; bcv=S.bc1[co]; }
    if (role == 1){ wzc=S.wz2+co*180; wrc=S.wr2+co*180; wcc=S.wc2+co*180; bzv=S.bz2[co]; brv=S.br2[co]; bcv=S.bc2[co]; }
    if (role == 2){ wzc=S.wz3+co*54;  wrc=S.wr3+co*54;  wcc=S.wc3+co*54;  bzv=S.bz3[co]; brv=S.br3[co]; bcv=S.bc3[co]; }

    float zsave = 0.f;   // z gate carried A->B in registers
    unsigned tgt = 0;    // monotonic barrier phase

    for (int k = 0; k < ND + 2; ++k) {
        // ---------------- PHASE A ----------------
        if (role == 0 && k < ND) {
            const int d = k;
            const TX* xd = (const TX*)S.xv + (size_t)d*NPIX*FC;
            const float* h1o = ((d-1)&1) ? S.h1b : S.h1a;
            float az = bzv, ar = brv;
#pragma unroll 1
            for (int ky=0; ky<3; ky++){
                int qy = py + ky - 1; if ((unsigned)qy >= (unsigned)FHh) continue;
#pragma unroll 1
                for (int kx=0; kx<3; kx++){
                    int qx = px + kx - 1; if ((unsigned)qx >= (unsigned)FWw) continue;
                    int q = qy*FWw + qx, j = ky*3 + kx;
                    const TX* xp = xd + (size_t)q*FC;
#pragma unroll
                    for (int ci=0; ci<32; ci++){
                        float v = ldx(xp + ci);
                        az = fmaf(wzc[ci*9+j], v, az);
                        ar = fmaf(wrc[ci*9+j], v, ar);
                    }
                    const float* hp = h1o + q*16;
#pragma unroll
                    for (int ci=0; ci<16; ci++){
                        float v = hp[ci];
                        az = fmaf(wzc[(32+ci)*9+j], v, az);
                        ar = fmaf(wrc[(32+ci)*9+j], v, ar);
                    }
                }
            }
            float z = sigm_(az), r = sigm_(ar);
            zsave = z;
            S.zg0[n*16+co] = z;
            S.rh0[n*16+co] = r * h1o[n*16+co];
        } else if (role == 1 && k >= 1 && k <= ND) {
            const int d = k - 1;
            const float* x2  = (d&1) ? S.h1b : S.h1a;      // h1 new of step d
            const float* h2o = ((d-1)&1) ? S.h2b : S.h2a;
            float az = bzv, ar = brv;
#pragma unroll 1
            for (int ky=0; ky<3; ky++){
                int qy = py + ky - 1; if ((unsigned)qy >= (unsigned)FHh) continue;
#pragma unroll 1
                for (int kx=0; kx<3; kx++){
                    int qx = px + kx - 1; if ((unsigned)qx >= (unsigned)FWw) continue;
                    int q = qy*FWw + qx, j = ky*3 + kx;
                    const float* xp = x2 + q*16;
#pragma unroll
                    for (int ci=0; ci<16; ci++){
                        float v = xp[ci];
                        az = fmaf(wzc[ci*9+j], v, az);
                        ar = fmaf(wrc[ci*9+j], v, ar);
                    }
                    const float* hp = h2o + q*4;
#pragma unroll
                    for (int ci=0; ci<4; ci++){
                        float v = hp[ci];
                        az = fmaf(wzc[(16+ci)*9+j], v, az);
                        ar = fmaf(wrc[(16+ci)*9+j], v, ar);
                    }
                }
            }
            float z = sigm_(az), r = sigm_(ar);
            zsave = z;
            S.zg1[n*4+co] = z;
            S.rh1[n*4+co] = r * h2o[n*4+co];
        } else if (role == 2 && k >= 2) {
            const int d = k - 2;
            const float* x3  = (d&1) ? S.h2b : S.h2a;      // h2 new of step d
            const float* h3o = ((d-1)&1) ? S.h3b : S.h3a;
            float az = bzv, ar = brv;
#pragma unroll 1
            for (int ky=0; ky<3; ky++){
                int qy = py + ky - 1; if ((unsigned)qy >= (unsigned)FHh) continue;
#pragma unroll 1
                for (int kx=0; kx<3; kx++){
                    int qx = px + kx - 1; if ((unsigned)qx >= (unsigned)FWw) continue;
                    int q = qy*FWw + qx, j = ky*3 + kx;
                    const float* xp = x3 + q*4;
#pragma unroll
                    for (int ci=0; ci<4; ci++){
                        float v = xp[ci];
                        az = fmaf(wzc[ci*9+j], v, az);
                        ar = fmaf(wrc[ci*9+j], v, ar);
                    }
                    const float* hp = h3o + q*2;
#pragma unroll
                    for (int ci=0; ci<2; ci++){
                        float v = hp[ci];
                        az = fmaf(wzc[(4+ci)*9+j], v, az);
                        ar = fmaf(wrc[(4+ci)*9+j], v, ar);
                    }
                }
            }
            float z = sigm_(az), r = sigm_(ar);
            zsave = z;
            S.zg2[n*2+co] = z;
            S.rh2[n*2+co] = r * h3o[n*2+co];
        }
        gsync(S, ++tgt);

        // ---------------- PHASE B ----------------
        if (role == 0 && k < ND) {
            const int d = k;
            const TX* xd = (const TX*)S.xv + (size_t)d*NPIX*FC;
            const float* h1o = ((d-1)&1) ? S.h1b : S.h1a;
            float*       h1n = (d&1)     ? S.h1b : S.h1a;
            float ac = bcv;
#pragma unroll 1
            for (int ky=0; ky<3; ky++){
                int qy = py + ky - 1; if ((unsigned)qy >= (unsigned)FHh) continue;
#pragma unroll 1
                for (int kx=0; kx<3; kx++){
                    int qx = px + kx - 1; if ((unsigned)qx >= (unsigned)FWw) continue;
                    int q = qy*FWw + qx, j = ky*3 + kx;
                    const TX* xp = xd + (size_t)q*FC;
#pragma unroll
                    for (int ci=0; ci<32; ci++)
                        ac = fmaf(wcc[ci*9+j], ldx(xp + ci), ac);
                    const float* rp = S.rh0 + q*16;
#pragma unroll
                    for (int ci=0; ci<16; ci++)
                        ac = fmaf(wcc[(32+ci)*9+j], rp[ci], ac);
                }
            }
            float cg = tanh_(ac);
            float z = zsave;
            h1n[n*16+co] = z*h1o[n*16+co] + (1.f - z)*cg;
        } else if (role == 1 && k >= 1 && k <= ND) {
            const int d = k - 1;
            const float* x2  = (d&1) ? S.h1b : S.h1a;
            const float* h2o = ((d-1)&1) ? S.h2b : S.h2a;
            float*       h2n = (d&1)     ? S.h2b : S.h2a;
            float ac = bcv;
#pragma unroll 1
            for (int ky=0; ky<3; ky++){
                int qy = py + ky - 1; if ((unsigned)qy >= (unsigned)FHh) continue;
#pragma unroll 1
                for (int kx=0; kx<3; kx++){
                    int qx = px + kx - 1; if ((unsigned)qx >= (unsigned)FWw) continue;
                    int q = qy*FWw + qx, j = ky*3 + kx;
                    const float* xp = x2 + q*16;
#pragma unroll
                    for (int ci=0; ci<16; ci++)
                        ac = fmaf(wcc[ci*9+j], xp[ci], ac);
                    const float* rp = S.rh1 + q*4;
#pragma unroll
                    for (int ci=0; ci<4; ci++)
                        ac = fmaf(wcc[(16+ci)*9+j], rp[ci], ac);
                }
            }
            float cg = tanh_(ac);
            float z = zsave;
            h2n[n*4+co] = z*h2o[n*4+co] + (1.f - z)*cg;
        } else if (role == 2 && k >= 2) {
            const int d = k - 2;
            const float* x3  = (d&1) ? S.h2b : S.h2a;
            const float* h3o = ((d-1)&1) ? S.h3b : S.h3a;
            float*       h3n = (d&1)     ? S.h3b : S.h3a;
            float ac = bcv;
#pragma unroll 1
            for (int ky=0; ky<3; ky++){
                int qy = py + ky - 1; if ((unsigned)qy >= (unsigned)FHh) continue;
#pragma unroll 1
                for (int kx=0; kx<3; kx++){
                    int qx = px + kx - 1; if ((unsigned)qx >= (unsigned)FWw) continue;
                    int q = qy*FWw + qx, j = ky*3 + kx;
                    const float* xp = x3 + q*4;
#pragma unroll
                    for (int ci=0; ci<4; ci++)
                        ac = fmaf(wcc[ci*9+j], xp[ci], ac);
                    const float* rp = S.rh2 + q*2;
                    ac = fmaf(wcc[4*9+j], rp[0], ac);
                    ac = fmaf(wcc[5*9+j], rp[1], ac);
                }
            }
            float cg = tanh_(ac);
            float z = zsave;
            h3n[n*2+co] = z*h3o[n*2+co] + (1.f - z)*cg;
        } else if (role == 3 && k >= 2) {
            // prob(d): recompute h3new at the 9 taps from zg2/rh2/h2new/h3old (no extra barrier)
            const int d = k - 2;
            const float* x3  = (d&1) ? S.h2b : S.h2a;
            const float* h3o = ((d-1)&1) ? S.h3b : S.h3a;
            float a = S.bp[0];
#pragma unroll 1
            for (int ky=0; ky<3; ky++){
                int qy = py + ky - 1; if ((unsigned)qy >= (unsigned)FHh) continue;
#pragma unroll 1
                for (int kx=0; kx<3; kx++){
                    int qx = px + kx - 1; if ((unsigned)qx >= (unsigned)FWw) continue;
                    int q = qy*FWw + qx;
#pragma unroll 1
                    for (int c2=0; c2<2; c2++){
                        const float* wc3c = S.wc3 + c2*54;
                        float ac = S.bc3[c2];
#pragma unroll 1
                        for (int jy=0; jy<3; jy++){
                            int ry = qy + jy - 1; if ((unsigned)ry >= (unsigned)FHh) continue;
#pragma unroll 1
                            for (int jx=0; jx<3; jx++){
                                int rx = qx + jx - 1; if ((unsigned)rx >= (unsigned)FWw) continue;
                                int rq = ry*FWw + rx, jj = jy*3 + jx;
                                const float* xp = x3 + rq*4;
#pragma unroll
                                for (int ci=0; ci<4; ci++)
                                    ac = fmaf(wc3c[ci*9+jj], xp[ci], ac);
                                const float* rp = S.rh2 + rq*2;
                                ac = fmaf(wc3c[4*9+jj], rp[0], ac);
                                ac = fmaf(wc3c[5*9+jj], rp[1], ac);
                            }
                        }
                        float cg = tanh_(ac);
                        float z = S.zg2[q*2+c2];
                        float h3n = z*h3o[q*2+c2] + (1.f - z)*cg;
                        a = fmaf(S.wp[c2*9 + ky*3 + kx], h3n, a);
                    }
                }
            }
            S.reg[(size_t)d*NPIX + n] = a;
        }
        gsync(S, ++tgt);
    }
}

// ---------------- softmax / depth regression (f32 out) ----------------
__global__ __launch_bounds__(256) void k_final(
    const float* __restrict__ reg, const float* __restrict__ su, float* __restrict__ out)
{
    int n = blockIdx.x*256 + threadIdx.x;
    if (n >= NPIX) return;
    float m = -1e30f;
    for (int d=0; d<ND; d++) m = fmaxf(m, reg[(size_t)d*NPIX + n]);
    float s = 0.f, acc = 0.f;
    for (int d=0; d<ND; d++){
        float e = expf(reg[(size_t)d*NPIX + n] - m);
        s += e;
        acc = fmaf(e, su[48+d], acc);
    }
    float inv_s = 1.f/s;
    float pred = acc * inv_s;
    float ds = su[176], di = su[177];
    int i0 = (int)floorf((pred - ds)/di);
    float pm = 0.f;
    for (int k=0; k<4; k++){
        int g = min(max(i0 - 1 + k, 0), ND-1);
        pm += expf(reg[(size_t)g*NPIX + n] - m);
    }
    pm *= inv_s;
    out[n]        = pred;
    out[NPIX + n] = pm;
}

// ---------------- host orchestration ----------------
extern "C" void kernel_launch(void* const* d_in, const int* in_sizes, int n_in,
                              void* d_out, int out_size, void* d_ws, size_t ws_size,
                              hipStream_t stream)
{
    (void)in_sizes; (void)n_in; (void)out_size;
    const float* img   = (const float*)d_in[0];
    const float* cam   = (const float*)d_in[1];
    const float* fe_w0 = (const float*)d_in[2];
    const float* fe_g0 = (const float*)d_in[3];
    const float* fe_b0 = (const float*)d_in[4];
    const float* fe_w1 = (const float*)d_in[5];
    const float* fe_g1 = (const float*)d_in[6];
    const float* fe_b1 = (const float*)d_in[7];
    const float* fe_w2 = (const float*)d_in[8];
    const float* fe_g2 = (const float*)d_in[9];
    const float* fe_b2 = (const float*)d_in[10];
    const float* fe_w3 = (const float*)d_in[11];
    const float* fe_b3 = (const float*)d_in[12];
    const float* gw[3][3]; const float* gb[3][3];
    for (int i=0;i<3;i++) for (int g=0; g<3; g++){
        gw[i][g] = (const float*)d_in[13 + i*6 + g*2];
        gb[i][g] = (const float*)d_in[13 + i*6 + g*2 + 1];
    }
    const float* prob_w = (const float*)d_in[31];
    const float* prob_b = (const float*)d_in[32];
    float* out = (float*)d_out;

    // workspace layout
    char* base = (char*)d_ws;
    size_t off = 0;
    auto alloc = [&](size_t bytes)->char*{
        char* p = base + off; off += (bytes + 255) & ~(size_t)255; return p;
    };
    float* su     = (float*)alloc(256*4);
    float* stats  = (float*)alloc(64*4);
    unsigned* gen    = (unsigned*)alloc(128);            // own cacheline
    unsigned* arrive = (unsigned*)alloc(NBLK*128);       // 128B per block
    float* buf0   = (float*)alloc((size_t)IMGS*8*H0*W0*4);
    float* buf1   = (float*)alloc((size_t)IMGS*16*H1*W1*4);
    float* buf2   = (float*)alloc((size_t)IMGS*32*NPIX*4);
    float* feats  = (float*)alloc((size_t)IMGS*32*NPIX*4);
    float* featst = (float*)alloc((size_t)IMGS*NPIX*FC*4);
    float* reg    = (float*)alloc((size_t)ND*NPIX*4);
    float* h1a = (float*)alloc(16*NPIX*4); float* h1b = (float*)alloc(16*NPIX*4);
    float* h2a = (float*)alloc(4*NPIX*4);  float* h2b = (float*)alloc(4*NPIX*4);
    float* h3a = (float*)alloc(2*NPIX*4);  float* h3b = (float*)alloc(2*NPIX*4);
    float* zg0 = (float*)alloc(16*NPIX*4);
    float* rh0 = (float*)alloc(16*NPIX*4);
    float* zg1 = (float*)alloc(4*NPIX*4);
    float* rh1 = (float*)alloc(4*NPIX*4);
    float* zg2 = (float*)alloc(2*NPIX*4);
    float* rh2 = (float*)alloc(2*NPIX*4);
    size_t off_common = off;
    // cost volume: f32 if workspace allows, else bf16
    bool xf32 = (ws_size >= off_common + (size_t)ND*FC*NPIX*4);
    void* xbuf = (void*)(base + off_common);

    // zero odd-parity h buffers (read at d=0 as h(-1)) and barrier state
    (void)hipMemsetAsync(h1b, 0, 16*NPIX*4, stream);
    (void)hipMemsetAsync(h2b, 0, 4*NPIX*4, stream);
    (void)hipMemsetAsync(h3b, 0, 2*NPIX*4, stream);
    (void)hipMemsetAsync(gen, 0, 128, stream);
    (void)hipMemsetAsync(arrive, 0, NBLK*128, stream);

    k_setup<<<1, 64, 0, stream>>>(cam, su);

    // ---- feature extraction ----
    k_conv3x3<<<dim3((H0*W0+255)/256, IMGS*8), 256, 3*9*4, stream>>>(
        img, fe_w0, nullptr, buf0, 3, H0, W0, 8, H0, W0, 1);
    k_gnstats<<<IMGS*1, 256, 0, stream>>>(buf0, stats, 8, H0*W0);
    k_gnapply<<<(IMGS*8*H0*W0+255)/256, 256, 0, stream>>>(
        buf0, stats, fe_g0, fe_b0, 8, H0*W0, 8*H0*W0, IMGS*8*H0*W0);
    k_conv3x3<<<dim3((H1*W1+255)/256, IMGS*16), 256, 8*9*4, stream>>>(
        buf0, fe_w1, nullptr, buf1, 8, H0, W0, 16, H1, W1, 2);
    k_gnstats<<<IMGS*2, 256, 0, stream>>>(buf1, stats, 8, H1*W1);
    k_gnapply<<<(IMGS*16*H1*W1+255)/256, 256, 0, stream>>>(
        buf1, stats, fe_g1, fe_b1, 16, H1*W1, 8*H1*W1, IMGS*16*H1*W1);
    k_conv3x3<<<dim3((NPIX+255)/256, IMGS*32), 256, 16*9*4, stream>>>(
        buf1, fe_w2, nullptr, buf2, 16, H1, W1, 32, FHh, FWw, 2);
    k_gnstats<<<IMGS*4, 256, 0, stream>>>(buf2, stats, 8, NPIX);
    k_gnapply<<<(IMGS*32*NPIX+255)/256, 256, 0, stream>>>(
        buf2, stats, fe_g2, fe_b2, 32, NPIX, 8*NPIX, IMGS*32*NPIX);
    k_conv3x3<<<dim3((NPIX+255)/256, IMGS*32), 256, 32*9*4, stream>>>(
        buf2, fe_w3, fe_b3, feats, 32, FHh, FWw, 32, FHh, FWw, 1);
    k_transpose<<<(IMGS*FC*NPIX+255)/256, 256, 0, stream>>>(feats, featst);

    // ---- warp + cost volume ----
    if (xf32) k_warpcost<float><<<ND*NPIX/256, 256, 0, stream>>>(featst, su, (float*)xbuf);
    else      k_warpcost<__hip_bfloat16><<<ND*NPIX/256, 256, 0, stream>>>(featst, su, (__hip_bfloat16*)xbuf);

    // ---- persistent pipelined GRU scan (1 kernel, 2 barriers/step) ----
    ScanArgs S;
    S.xv = xbuf;
    S.wz1=gw[0][0]; S.bz1=gb[0][0]; S.wr1=gw[0][1]; S.br1=gb[0][1]; S.wc1=gw[0][2]; S.bc1=gb[0][2];
    S.wz2=gw[1][0]; S.bz2=gb[1][0]; S.wr2=gw[1][1]; S.br2=gb[1][1]; S.wc2=gw[1][2]; S.bc2=gb[1][2];
    S.wz3=gw[2][0]; S.bz3=gb[2][0]; S.wr3=gw[2][1]; S.br3=gb[2][1]; S.wc3=gw[2][2]; S.bc3=gb[2][2];
    S.wp=prob_w; S.bp=prob_b;
    S.h1a=h1a; S.h1b=h1b; S.h2a=h2a; S.h2b=h2b; S.h3a=h3a; S.h3b=h3b;
    S.zg0=zg0; S.rh0=rh0; S.zg1=zg1; S.rh1=rh1; S.zg2=zg2; S.rh2=rh2;
    S.reg=reg; S.gen=gen; S.arrive=arrive;
    if (xf32) k_scan<float><<<NBLK, 256, 0, stream>>>(S);
    else      k_scan<__hip_bfloat16><<<NBLK, 256, 0, stream>>>(S);

    // ---- softmax + depth regression + prob map ----
    k_final<<<NPIX/256, 256, 0, stream>>>(reg, su, out);
}